// Round 8
// baseline (232.710 us; speedup 1.0000x reference)
//
#include <hip/hip_runtime.h>

#define NN 50000
#define NE 600000
#define MAXD 64
#define ZB ((NN + 255) / 256)    // 196 zero blocks

typedef __attribute__((ext_vector_type(8))) short short8;   // 8 bf16 = 4 VGPR
typedef __attribute__((ext_vector_type(4))) float floatx4;  // MFMA acc

__device__ __forceinline__ float b2f(unsigned short u) {
    return __uint_as_float((unsigned)u << 16);
}
__device__ __forceinline__ unsigned short f2b(float f) {
    unsigned u = __float_as_uint(f);
    return (unsigned short)((u + 0x7FFF + ((u >> 16) & 1)) >> 16);
}

// ---------------------------------------------------------------------------
// Fused init: blocks [0,152) convert weights fp32->bf16 into Wb
// ([0,16384) W1b | [16384,32768) W2b | [32768,38912) Wfcb 48 rows, 40..47
// zero); blocks [152,152+ZB) zero the ELL counts.
// ---------------------------------------------------------------------------
__global__ __launch_bounds__(256) void init_k(
    const float* __restrict__ W1, const float* __restrict__ W2,
    const float* __restrict__ Wfc, unsigned short* __restrict__ Wb,
    int* __restrict__ counts)
{
    int blk = blockIdx.x;
    int t = threadIdx.x;
    if (blk < 152) {
        int id = blk * 256 + t;
        if (id < 16384) {
            Wb[id] = f2b(W1[id]);
        } else if (id < 32768) {
            Wb[id] = f2b(W2[id - 16384]);
        } else {
            int k = id - 32768;
            int r = k >> 7, c = k & 127;
            Wb[id] = (r < 40) ? f2b(Wfc[r * 128 + c]) : (unsigned short)0;
        }
    } else {
        int i = (blk - 152) * 256 + t;
        if (i < NN) counts[i] = 0;
    }
}

// ---------------------------------------------------------------------------
// ELL fill: slot[d*MAXD + p] = s for each edge (s,d).
// ---------------------------------------------------------------------------
__global__ __launch_bounds__(256) void fill_k(
    const int* __restrict__ src, const int* __restrict__ dst,
    int* __restrict__ counts, int* __restrict__ slot, int E)
{
    int id = blockIdx.x * 256 + threadIdx.x;
    if (id < E) {
        int d = dst[id], s = src[id];
        int p = atomicAdd(&counts[d], 1);
        if (p < MAXD) slot[d * MAXD + p] = s;
    }
}

// ---------------------------------------------------------------------------
// MFMA GEMM + bias + relu, fp32 X input, bf16 W:
//   Y[n][j] = bf16(relu(sum_k X[n][k]*W[j][k] + b[j]))
// 256 thr = 4 waves, 64 nodes x 128 j; wave: 16 nodes, 8 j-tiles, 4 k-chunks.
// ---------------------------------------------------------------------------
__global__ __launch_bounds__(256) void gemm_mfma_f32in_k(
    const float* __restrict__ X, const unsigned short* __restrict__ Wb,
    const float* __restrict__ b, unsigned short* __restrict__ Y, int N)
{
    __shared__ __align__(16) unsigned short Xs[64 * 136];
    __shared__ __align__(16) unsigned short Ws[128 * 136];
    const int t  = threadIdx.x;
    const int n0 = blockIdx.x * 64;

#pragma unroll
    for (int i = 0; i < 8; ++i) {
        int f = t + i * 256;
        int r = f >> 5, kq = f & 31;
        float4 v = make_float4(0.f, 0.f, 0.f, 0.f);
        if (n0 + r < N) v = ((const float4*)(X + (size_t)(n0 + r) * 128))[kq];
        *(ushort4*)&Xs[r * 136 + kq * 4] =
            make_ushort4(f2b(v.x), f2b(v.y), f2b(v.z), f2b(v.w));
    }
#pragma unroll
    for (int i = 0; i < 8; ++i) {
        int f = t + i * 256;
        int r = f >> 4, c = f & 15;
        *(short8*)&Ws[r * 136 + c * 8] = *(const short8*)(Wb + r * 128 + c * 8);
    }
    __syncthreads();

    const int w = t >> 6, lane = t & 63;
    const int m = lane & 15, q = lane >> 4;

    short8 a[4];
#pragma unroll
    for (int kc = 0; kc < 4; ++kc)
        a[kc] = *(const short8*)&Xs[(16 * w + m) * 136 + kc * 32 + q * 8];

    floatx4 acc[8];
#pragma unroll
    for (int jt = 0; jt < 8; ++jt) {
        floatx4 c = {0.f, 0.f, 0.f, 0.f};
#pragma unroll
        for (int kc = 0; kc < 4; ++kc) {
            short8 bb = *(const short8*)&Ws[(16 * jt + m) * 136 + kc * 32 + q * 8];
            c = __builtin_amdgcn_mfma_f32_16x16x32_bf16(a[kc], bb, c, 0, 0, 0);
        }
        acc[jt] = c;
    }

    // D layout: col = lane&15, row = (lane>>4)*4 + reg
#pragma unroll
    for (int jt = 0; jt < 8; ++jt) {
        int j = 16 * jt + m;
        float bj = b[j];
#pragma unroll
        for (int r = 0; r < 4; ++r) {
            int node = n0 + 16 * w + q * 4 + r;
            if (node < N) {
                float v = acc[jt][r] + bj;
                Y[(size_t)node * 128 + j] = f2b(v > 0.f ? v : 0.f);
            }
        }
    }
}

// ---------------------------------------------------------------------------
// Fused ELL-gather + GEMM2 + FC:
//   x1[n][:] = sum_p H[slot[n*64+p]][:]           (gathered into LDS Xs)
//   h = relu(x1 W2^T + b2)                        (LDS round-trip, bf16)
//   G[n][j] = bf16(sum_k h[n][k]*Wfc[j][k]), j<40, stride 64.
// Gather: each wave owns 16 node-rows; per node 4 edge slots x unroll2 = 8
// row loads in flight; butterfly across lane^16/^32; e4==0 lanes write LDS.
// W2 staging is issued first so its loads overlap the gather latency.
// ---------------------------------------------------------------------------
__global__ __launch_bounds__(256) void agg_gemm2fc_k(
    const unsigned short* __restrict__ H, const int* __restrict__ counts,
    const int* __restrict__ slot, const unsigned short* __restrict__ W2b,
    const float* __restrict__ b2, const unsigned short* __restrict__ Wfcb,
    unsigned short* __restrict__ G, int N)
{
    __shared__ __align__(16) unsigned short Xs[64 * 136];
    __shared__ __align__(16) unsigned short Ws[128 * 136];
    const int t  = threadIdx.x;
    const int n0 = blockIdx.x * 64;
    const int w = t >> 6, lane = t & 63;
    const int e4 = lane >> 4;       // edge-slot group 0..3
    const int c8 = lane & 15;       // col group: cols 8*c8..8*c8+7

    // stage W2 (issue first: overlaps the gather)
#pragma unroll
    for (int i = 0; i < 8; ++i) {
        int f = t + i * 256;
        int r = f >> 4, c = f & 15;
        *(short8*)&Ws[r * 136 + c * 8] = *(const short8*)(W2b + r * 128 + c * 8);
    }

    // gather 16 node-rows per wave directly into Xs
    for (int nl = 0; nl < 16; ++nl) {
        int node = n0 + 16 * w + nl;
        float acc[8] = {};
        if (node < N) {
            int beg = node * MAXD;
            int end = beg + min(counts[node], MAXD);
            int i = beg + e4;
            for (; i + 4 < end; i += 8) {
                int s0 = slot[i], s1 = slot[i + 4];
                short8 a = *(const short8*)(H + (size_t)s0 * 128 + c8 * 8);
                short8 b = *(const short8*)(H + (size_t)s1 * 128 + c8 * 8);
#pragma unroll
                for (int j = 0; j < 8; ++j)
                    acc[j] += b2f((unsigned short)a[j]) + b2f((unsigned short)b[j]);
            }
            if (i < end) {
                int s0 = slot[i];
                short8 a = *(const short8*)(H + (size_t)s0 * 128 + c8 * 8);
#pragma unroll
                for (int j = 0; j < 8; ++j)
                    acc[j] += b2f((unsigned short)a[j]);
            }
        }
#pragma unroll
        for (int j = 0; j < 8; ++j) {
            acc[j] += __shfl(acc[j], lane ^ 16);
            acc[j] += __shfl(acc[j], lane ^ 32);
        }
        if (e4 == 0) {
            short8 o;
#pragma unroll
            for (int j = 0; j < 8; ++j) o[j] = (short)f2b(acc[j]);
            *(short8*)&Xs[(16 * w + nl) * 136 + c8 * 8] = o;
        }
    }
    __syncthreads();

    const int m = lane & 15, q = lane >> 4;

    short8 a[4];
#pragma unroll
    for (int kc = 0; kc < 4; ++kc)
        a[kc] = *(const short8*)&Xs[(16 * w + m) * 136 + kc * 32 + q * 8];

    floatx4 acc[8];
#pragma unroll
    for (int jt = 0; jt < 8; ++jt) {
        floatx4 c = {0.f, 0.f, 0.f, 0.f};
#pragma unroll
        for (int kc = 0; kc < 4; ++kc) {
            short8 bb = *(const short8*)&Ws[(16 * jt + m) * 136 + kc * 32 + q * 8];
            c = __builtin_amdgcn_mfma_f32_16x16x32_bf16(a[kc], bb, c, 0, 0, 0);
        }
        acc[jt] = c;
    }

    // relu(acc + b2) -> bf16 -> back into Xs (each wave owns rows 16w..16w+15)
#pragma unroll
    for (int jt = 0; jt < 8; ++jt) {
        int j = 16 * jt + m;
        float bj = b2[j];
#pragma unroll
        for (int r = 0; r < 4; ++r) {
            float v = acc[jt][r] + bj;
            Xs[(16 * w + q * 4 + r) * 136 + j] = f2b(v > 0.f ? v : 0.f);
        }
    }
    __syncthreads();                 // all W2 reads + h writes complete

    // re-stage Wfc (48 rows) over Ws
#pragma unroll
    for (int i = 0; i < 3; ++i) {
        int f = t + i * 256;
        int r = f >> 4, c = f & 15;
        *(short8*)&Ws[r * 136 + c * 8] = *(const short8*)(Wfcb + r * 128 + c * 8);
    }
    __syncthreads();

    short8 a2[4];
#pragma unroll
    for (int kc = 0; kc < 4; ++kc)
        a2[kc] = *(const short8*)&Xs[(16 * w + m) * 136 + kc * 32 + q * 8];

#pragma unroll
    for (int jt = 0; jt < 3; ++jt) {
        floatx4 c = {0.f, 0.f, 0.f, 0.f};
#pragma unroll
        for (int kc = 0; kc < 4; ++kc) {
            short8 bb = *(const short8*)&Ws[(16 * jt + m) * 136 + kc * 32 + q * 8];
            c = __builtin_amdgcn_mfma_f32_16x16x32_bf16(a2[kc], bb, c, 0, 0, 0);
        }
        int j = 16 * jt + m;
        if (j < 40) {
#pragma unroll
            for (int r = 0; r < 4; ++r) {
                int node = n0 + 16 * w + q * 4 + r;
                if (node < N) G[(size_t)node * 64 + j] = f2b(c[r]);
            }
        }
    }
}

// ---------------------------------------------------------------------------
// Gather-sum 40-wide + bias (bf16 in stride 64, fp32 out), ELL.
// ---------------------------------------------------------------------------
__global__ __launch_bounds__(256) void agg40_k(
    const unsigned short* __restrict__ G, const int* __restrict__ counts,
    const int* __restrict__ slot, const float* __restrict__ bfc,
    float* __restrict__ OUT, int N)
{
    int node = (blockIdx.x * 256 + threadIdx.x) >> 6;
    int lane = threadIdx.x & 63;
    if (node >= N) return;
    int e4 = lane >> 4;
    int c4 = lane & 15;
    int beg = node * MAXD;
    int end = beg + min(counts[node], MAXD);
    float acc[4] = {};

    int i = beg + e4;
    for (; i + 4 < end; i += 8) {
        int s0 = slot[i], s1 = slot[i + 4];
        ushort4 a = *(const ushort4*)(G + (size_t)s0 * 64 + c4 * 4);
        ushort4 b = *(const ushort4*)(G + (size_t)s1 * 64 + c4 * 4);
        acc[0] += b2f(a.x) + b2f(b.x);
        acc[1] += b2f(a.y) + b2f(b.y);
        acc[2] += b2f(a.z) + b2f(b.z);
        acc[3] += b2f(a.w) + b2f(b.w);
    }
    if (i < end) {
        int s0 = slot[i];
        ushort4 a = *(const ushort4*)(G + (size_t)s0 * 64 + c4 * 4);
        acc[0] += b2f(a.x); acc[1] += b2f(a.y);
        acc[2] += b2f(a.z); acc[3] += b2f(a.w);
    }
#pragma unroll
    for (int j = 0; j < 4; ++j) {
        acc[j] += __shfl(acc[j], lane ^ 16);
        acc[j] += __shfl(acc[j], lane ^ 32);
    }
    if (e4 == 0 && c4 < 10) {
        float4 r = make_float4(acc[0] + bfc[c4 * 4 + 0],
                               acc[1] + bfc[c4 * 4 + 1],
                               acc[2] + bfc[c4 * 4 + 2],
                               acc[3] + bfc[c4 * 4 + 3]);
        *(float4*)(OUT + (size_t)node * 40 + c4 * 4) = r;
    }
}

extern "C" void kernel_launch(void* const* d_in, const int* in_sizes, int n_in,
                              void* d_out, int out_size, void* d_ws, size_t ws_size,
                              hipStream_t stream)
{
    const float* X    = (const float*)d_in[0];
    const float* W1   = (const float*)d_in[1];
    const float* b1   = (const float*)d_in[2];
    const float* W2   = (const float*)d_in[3];
    const float* b2   = (const float*)d_in[4];
    const float* Wfc  = (const float*)d_in[5];
    const float* bfc  = (const float*)d_in[6];
    const int*   esrc = (const int*)d_in[7];
    const int*   edst = (const int*)d_in[8];
    float* out = (float*)d_out;

    // Workspace layout (~32.4 MB):
    unsigned short* h = (unsigned short*)d_ws;          // bf16 [NN,128]
    unsigned short* g = h + (size_t)NN * 128;           // bf16 [NN,64]
    int* counts = (int*)(g + (size_t)NN * 64);          // NN
    int* slot   = counts + NN;                          // NN*MAXD
    unsigned short* Wb = (unsigned short*)(slot + (size_t)NN * MAXD); // 38912

    // 1. fused init: weights->bf16 + zero ELL counts
    init_k<<<152 + ZB, 256, 0, stream>>>(W1, W2, Wfc, Wb, counts);
    // 2. ELL fill
    fill_k<<<(NE + 255) / 256, 256, 0, stream>>>(esrc, edst, counts, slot, NE);

    const int GB = (NN + 63) / 64;
    // 3. layer 1 GEMM -> h
    gemm_mfma_f32in_k<<<GB, 256, 0, stream>>>(X, Wb, b1, h, NN);
    // 4. fused: ELL-gather(h) + GEMM2 + FC -> g
    agg_gemm2fc_k<<<GB, 256, 0, stream>>>(h, counts, slot, Wb + 16384, b2,
                                          Wb + 32768, g, NN);
    // 5. aggregate 40-wide + bias -> out
    agg40_k<<<(NN * 64) / 256, 256, 0, stream>>>(g, counts, slot, bfc, out, NN);
}

// Round 9
// 209.680 us; speedup vs baseline: 1.1098x; 1.1098x over previous
//
#include <hip/hip_runtime.h>

#define NN 50000
#define NE 600000
#define MAXD 64
#define ZB ((NN + 255) / 256)    // 196 zero blocks
#define GB ((NN + 63) / 64)      // 782 gemm blocks
#define FB ((NE + 255) / 256)    // 2344 fill blocks

typedef __attribute__((ext_vector_type(8))) short short8;   // 8 bf16 = 4 VGPR
typedef __attribute__((ext_vector_type(4))) float floatx4;  // MFMA acc

__device__ __forceinline__ float b2f(unsigned short u) {
    return __uint_as_float((unsigned)u << 16);
}
__device__ __forceinline__ unsigned short f2b(float f) {
    unsigned u = __float_as_uint(f);
    return (unsigned short)((u + 0x7FFF + ((u >> 16) & 1)) >> 16);
}

// ---------------------------------------------------------------------------
// Fused init: blocks [0,152) convert weights fp32->bf16 into Wb
// ([0,16384) W1b | [16384,32768) W2b | [32768,38912) Wfcb 48 rows, 40..47
// zero); blocks [152,152+ZB) zero the ELL counts.
// ---------------------------------------------------------------------------
__global__ __launch_bounds__(256) void init_k(
    const float* __restrict__ W1, const float* __restrict__ W2,
    const float* __restrict__ Wfc, unsigned short* __restrict__ Wb,
    int* __restrict__ counts)
{
    int blk = blockIdx.x;
    int t = threadIdx.x;
    if (blk < 152) {
        int id = blk * 256 + t;
        if (id < 16384) {
            Wb[id] = f2b(W1[id]);
        } else if (id < 32768) {
            Wb[id] = f2b(W2[id - 16384]);
        } else {
            int k = id - 32768;
            int r = k >> 7, c = k & 127;
            Wb[id] = (r < 40) ? f2b(Wfc[r * 128 + c]) : (unsigned short)0;
        }
    } else {
        int i = (blk - 152) * 256 + t;
        if (i < NN) counts[i] = 0;
    }
}

// ---------------------------------------------------------------------------
// Mega kernel: blocks [0,GB) = layer-1 MFMA GEMM (+bias+relu, fp32 X, bf16 W)
//              blocks [GB,GB+FB) = ELL fill (the only edge-atomic pass).
// The two populations are independent; co-dispatching overlaps fill's
// atomic latency with the GEMM's MFMA pipe. NOTE: gather kernels must NOT
// be fused like this (R8: occupancy-starved); fill is not MLP-sensitive.
// ---------------------------------------------------------------------------
__global__ __launch_bounds__(256) void mega_k(
    const float* __restrict__ X, const unsigned short* __restrict__ Wb,
    const float* __restrict__ b, unsigned short* __restrict__ Y,
    const int* __restrict__ src, const int* __restrict__ dst,
    int* __restrict__ counts, int* __restrict__ slot, int N, int E)
{
    __shared__ __align__(16) unsigned short Xs[64 * 136];
    __shared__ __align__(16) unsigned short Ws[128 * 136];
    const int t = threadIdx.x;

    if (blockIdx.x >= GB) {
        // ---- ELL fill ----
        int id = (blockIdx.x - GB) * 256 + t;
        if (id < E) {
            int d = dst[id], s = src[id];
            int p = atomicAdd(&counts[d], 1);
            if (p < MAXD) slot[d * MAXD + p] = s;
        }
        return;
    }

    // ---- layer-1 GEMM ----
    const int n0 = blockIdx.x * 64;

#pragma unroll
    for (int i = 0; i < 8; ++i) {
        int f = t + i * 256;
        int r = f >> 5, kq = f & 31;
        float4 v = make_float4(0.f, 0.f, 0.f, 0.f);
        if (n0 + r < N) v = ((const float4*)(X + (size_t)(n0 + r) * 128))[kq];
        *(ushort4*)&Xs[r * 136 + kq * 4] =
            make_ushort4(f2b(v.x), f2b(v.y), f2b(v.z), f2b(v.w));
    }
#pragma unroll
    for (int i = 0; i < 8; ++i) {
        int f = t + i * 256;
        int r = f >> 4, c = f & 15;
        *(short8*)&Ws[r * 136 + c * 8] = *(const short8*)(Wb + r * 128 + c * 8);
    }
    __syncthreads();

    const int w = t >> 6, lane = t & 63;
    const int m = lane & 15, q = lane >> 4;

    short8 a[4];
#pragma unroll
    for (int kc = 0; kc < 4; ++kc)
        a[kc] = *(const short8*)&Xs[(16 * w + m) * 136 + kc * 32 + q * 8];

    floatx4 acc[8];
#pragma unroll
    for (int jt = 0; jt < 8; ++jt) {
        floatx4 c = {0.f, 0.f, 0.f, 0.f};
#pragma unroll
        for (int kc = 0; kc < 4; ++kc) {
            short8 bb = *(const short8*)&Ws[(16 * jt + m) * 136 + kc * 32 + q * 8];
            c = __builtin_amdgcn_mfma_f32_16x16x32_bf16(a[kc], bb, c, 0, 0, 0);
        }
        acc[jt] = c;
    }

    // D layout: col = lane&15, row = (lane>>4)*4 + reg
#pragma unroll
    for (int jt = 0; jt < 8; ++jt) {
        int j = 16 * jt + m;
        float bj = b[j];
#pragma unroll
        for (int r = 0; r < 4; ++r) {
            int node = n0 + 16 * w + q * 4 + r;
            if (node < N) {
                float v = acc[jt][r] + bj;
                Y[(size_t)node * 128 + j] = f2b(v > 0.f ? v : 0.f);
            }
        }
    }
}

// ---------------------------------------------------------------------------
// Fused GEMM2 + FC (standalone, high-occupancy gather stays separate):
//   h = relu(Xb W2^T + b2) [kept in LDS, bf16];
//   G[n][j] = bf16(sum_k h[n][k]*Wfc[j][k]), j<40, stride 64.
// ---------------------------------------------------------------------------
__global__ __launch_bounds__(256) void gemm2fc_k(
    const unsigned short* __restrict__ Xb, const unsigned short* __restrict__ W2b,
    const float* __restrict__ b2, const unsigned short* __restrict__ Wfcb,
    unsigned short* __restrict__ G, int N)
{
    __shared__ __align__(16) unsigned short Xs[64 * 136];
    __shared__ __align__(16) unsigned short Ws[128 * 136];
    const int t  = threadIdx.x;
    const int n0 = blockIdx.x * 64;

#pragma unroll
    for (int i = 0; i < 4; ++i) {
        int f = t + i * 256;
        int r = f >> 4, c = f & 15;
        short8 v = {0, 0, 0, 0, 0, 0, 0, 0};
        if (n0 + r < N)
            v = *(const short8*)(Xb + (size_t)(n0 + r) * 128 + c * 8);
        *(short8*)&Xs[r * 136 + c * 8] = v;
    }
#pragma unroll
    for (int i = 0; i < 8; ++i) {
        int f = t + i * 256;
        int r = f >> 4, c = f & 15;
        *(short8*)&Ws[r * 136 + c * 8] = *(const short8*)(W2b + r * 128 + c * 8);
    }
    __syncthreads();

    const int w = t >> 6, lane = t & 63;
    const int m = lane & 15, q = lane >> 4;

    short8 a[4];
#pragma unroll
    for (int kc = 0; kc < 4; ++kc)
        a[kc] = *(const short8*)&Xs[(16 * w + m) * 136 + kc * 32 + q * 8];

    floatx4 acc[8];
#pragma unroll
    for (int jt = 0; jt < 8; ++jt) {
        floatx4 c = {0.f, 0.f, 0.f, 0.f};
#pragma unroll
        for (int kc = 0; kc < 4; ++kc) {
            short8 bb = *(const short8*)&Ws[(16 * jt + m) * 136 + kc * 32 + q * 8];
            c = __builtin_amdgcn_mfma_f32_16x16x32_bf16(a[kc], bb, c, 0, 0, 0);
        }
        acc[jt] = c;
    }

    // relu(acc + b2) -> bf16 -> back into Xs (each wave owns rows 16w..16w+15)
#pragma unroll
    for (int jt = 0; jt < 8; ++jt) {
        int j = 16 * jt + m;
        float bj = b2[j];
#pragma unroll
        for (int r = 0; r < 4; ++r) {
            float v = acc[jt][r] + bj;
            Xs[(16 * w + q * 4 + r) * 136 + j] = f2b(v > 0.f ? v : 0.f);
        }
    }
    __syncthreads();                 // all W2 reads + h writes complete

    // re-stage Wfc (48 rows) over Ws
#pragma unroll
    for (int i = 0; i < 3; ++i) {
        int f = t + i * 256;
        int r = f >> 4, c = f & 15;
        *(short8*)&Ws[r * 136 + c * 8] = *(const short8*)(Wfcb + r * 128 + c * 8);
    }
    __syncthreads();

    short8 a2[4];
#pragma unroll
    for (int kc = 0; kc < 4; ++kc)
        a2[kc] = *(const short8*)&Xs[(16 * w + m) * 136 + kc * 32 + q * 8];

#pragma unroll
    for (int jt = 0; jt < 3; ++jt) {
        floatx4 c = {0.f, 0.f, 0.f, 0.f};
#pragma unroll
        for (int kc = 0; kc < 4; ++kc) {
            short8 bb = *(const short8*)&Ws[(16 * jt + m) * 136 + kc * 32 + q * 8];
            c = __builtin_amdgcn_mfma_f32_16x16x32_bf16(a2[kc], bb, c, 0, 0, 0);
        }
        int j = 16 * jt + m;
        if (j < 40) {
#pragma unroll
            for (int r = 0; r < 4; ++r) {
                int node = n0 + 16 * w + q * 4 + r;
                if (node < N) G[(size_t)node * 64 + j] = f2b(c[r]);
            }
        }
    }
}

// ---------------------------------------------------------------------------
// Gather-sum 128-wide (bf16 in/out), ELL: X[n][:] = sum_p H[slot[n*64+p]][:]
// One wave per node; 4 edge slots (16 lanes x ushort8), unroll x2 -> 8 row
// loads in flight. Butterfly across lane^16, ^32. Keep standalone: needs
// max occupancy (R8 lesson).
// ---------------------------------------------------------------------------
__global__ __launch_bounds__(256) void agg128_k(
    const unsigned short* __restrict__ H, const int* __restrict__ counts,
    const int* __restrict__ slot, unsigned short* __restrict__ X, int N)
{
    int node = (blockIdx.x * 256 + threadIdx.x) >> 6;
    int lane = threadIdx.x & 63;
    if (node >= N) return;
    int e4 = lane >> 4;
    int c8 = lane & 15;
    int beg = node * MAXD;
    int end = beg + min(counts[node], MAXD);
    float acc[8] = {};

    int i = beg + e4;
    for (; i + 4 < end; i += 8) {
        int s0 = slot[i], s1 = slot[i + 4];
        short8 a = *(const short8*)(H + (size_t)s0 * 128 + c8 * 8);
        short8 b = *(const short8*)(H + (size_t)s1 * 128 + c8 * 8);
#pragma unroll
        for (int j = 0; j < 8; ++j)
            acc[j] += b2f((unsigned short)a[j]) + b2f((unsigned short)b[j]);
    }
    if (i < end) {
        int s0 = slot[i];
        short8 a = *(const short8*)(H + (size_t)s0 * 128 + c8 * 8);
#pragma unroll
        for (int j = 0; j < 8; ++j)
            acc[j] += b2f((unsigned short)a[j]);
    }
#pragma unroll
    for (int j = 0; j < 8; ++j) {
        acc[j] += __shfl(acc[j], lane ^ 16);
        acc[j] += __shfl(acc[j], lane ^ 32);
    }
    if (e4 == 0) {
        short8 o;
#pragma unroll
        for (int j = 0; j < 8; ++j) o[j] = (short)f2b(acc[j]);
        *(short8*)(X + (size_t)node * 128 + c8 * 8) = o;
    }
}

// ---------------------------------------------------------------------------
// Gather-sum 40-wide + bias (bf16 in stride 64, fp32 out), ELL.
// ---------------------------------------------------------------------------
__global__ __launch_bounds__(256) void agg40_k(
    const unsigned short* __restrict__ G, const int* __restrict__ counts,
    const int* __restrict__ slot, const float* __restrict__ bfc,
    float* __restrict__ OUT, int N)
{
    int node = (blockIdx.x * 256 + threadIdx.x) >> 6;
    int lane = threadIdx.x & 63;
    if (node >= N) return;
    int e4 = lane >> 4;
    int c4 = lane & 15;
    int beg = node * MAXD;
    int end = beg + min(counts[node], MAXD);
    float acc[4] = {};

    int i = beg + e4;
    for (; i + 4 < end; i += 8) {
        int s0 = slot[i], s1 = slot[i + 4];
        ushort4 a = *(const ushort4*)(G + (size_t)s0 * 64 + c4 * 4);
        ushort4 b = *(const ushort4*)(G + (size_t)s1 * 64 + c4 * 4);
        acc[0] += b2f(a.x) + b2f(b.x);
        acc[1] += b2f(a.y) + b2f(b.y);
        acc[2] += b2f(a.z) + b2f(b.z);
        acc[3] += b2f(a.w) + b2f(b.w);
    }
    if (i < end) {
        int s0 = slot[i];
        ushort4 a = *(const ushort4*)(G + (size_t)s0 * 64 + c4 * 4);
        acc[0] += b2f(a.x); acc[1] += b2f(a.y);
        acc[2] += b2f(a.z); acc[3] += b2f(a.w);
    }
#pragma unroll
    for (int j = 0; j < 4; ++j) {
        acc[j] += __shfl(acc[j], lane ^ 16);
        acc[j] += __shfl(acc[j], lane ^ 32);
    }
    if (e4 == 0 && c4 < 10) {
        float4 r = make_float4(acc[0] + bfc[c4 * 4 + 0],
                               acc[1] + bfc[c4 * 4 + 1],
                               acc[2] + bfc[c4 * 4 + 2],
                               acc[3] + bfc[c4 * 4 + 3]);
        *(float4*)(OUT + (size_t)node * 40 + c4 * 4) = r;
    }
}

extern "C" void kernel_launch(void* const* d_in, const int* in_sizes, int n_in,
                              void* d_out, int out_size, void* d_ws, size_t ws_size,
                              hipStream_t stream)
{
    const float* X    = (const float*)d_in[0];
    const float* W1   = (const float*)d_in[1];
    const float* b1   = (const float*)d_in[2];
    const float* W2   = (const float*)d_in[3];
    const float* b2   = (const float*)d_in[4];
    const float* Wfc  = (const float*)d_in[5];
    const float* bfc  = (const float*)d_in[6];
    const int*   esrc = (const int*)d_in[7];
    const int*   edst = (const int*)d_in[8];
    float* out = (float*)d_out;

    // Workspace layout (~38.7 MB):
    unsigned short* h   = (unsigned short*)d_ws;        // bf16 [NN,128]
    unsigned short* x1b = h + (size_t)NN * 128;         // bf16 [NN,128]
    unsigned short* g   = h;                            // bf16 [NN,64] alias
                                                        //  (h dead after agg128)
    int* counts = (int*)(x1b + (size_t)NN * 128);       // NN
    int* slot   = counts + NN;                          // NN*MAXD
    unsigned short* Wb = (unsigned short*)(slot + (size_t)NN * MAXD); // 38912

    // 1. fused init: weights->bf16 + zero ELL counts
    init_k<<<152 + ZB, 256, 0, stream>>>(W1, W2, Wfc, Wb, counts);
    // 2. mega: layer-1 GEMM (blocks [0,GB)) + ELL fill (blocks [GB,GB+FB))
    mega_k<<<GB + FB, 256, 0, stream>>>(X, Wb, b1, h, esrc, edst,
                                        counts, slot, NN, NE);
    // 3. aggregate 128-wide -> x1b
    agg128_k<<<(NN * 64) / 256, 256, 0, stream>>>(h, counts, slot, x1b, NN);
    // 4. fused layer-2 GEMM + FC -> g
    gemm2fc_k<<<GB, 256, 0, stream>>>(x1b, Wb + 16384, b2, Wb + 32768, g, NN);
    // 5. aggregate 40-wide + bias -> out
    agg40_k<<<(NN * 64) / 256, 256, 0, stream>>>(g, counts, slot, bfc, out, NN);
}